// Round 6
// baseline (425.606 us; speedup 1.0000x reference)
//
#include <hip/hip_runtime.h>
#include <math.h>

#define F_IN 128
#define HID  64
#define NCLS 40
#define HCHUNK 4096
#define PCHUNK 8192
#define MAXNB 1024

typedef _Float16 half8 __attribute__((ext_vector_type(8)));
typedef float floatx4 __attribute__((ext_vector_type(4)));

// load 8 f16 from an 8B-aligned (not necessarily 16B) pointer (LDS staging use)
__device__ inline half8 ld_half8_u8(const _Float16* p) {
    union { uint2 u[2]; half8 h; } r;
    r.u[0] = *(const uint2*)p;
    r.u[1] = *(const uint2*)(p + 4);
    return r.h;
}

// ---------------- bucket-level histogram (LDS-privatized, 782 bins) ----------------
__global__ __launch_bounds__(256) void bucket_histo(const int* __restrict__ dst, int E,
                                                    int* __restrict__ bCnt, int NB) {
    __shared__ int h[MAXNB];
    int tid = threadIdx.x;
    for (int i = tid; i < NB; i += 256) h[i] = 0;
    __syncthreads();
    int e0 = blockIdx.x * HCHUNK;
    int eend = e0 + HCHUNK; if (eend > E) eend = E;
    for (int e = e0 + tid; e < eend; e += 256)
        atomicAdd(&h[dst[e] >> 7], 1);
    __syncthreads();
    for (int b = tid; b < NB; b += 256) {
        int c = h[b];
        if (c) atomicAdd(&bCnt[b], c);
    }
}

// ---------------- single-block exclusive scan of bucket counts ----------------
__global__ __launch_bounds__(256) void scan_buckets(const int* __restrict__ bCnt,
                                                    int* __restrict__ bBase,
                                                    int* __restrict__ bCur, int NB, int E) {
    __shared__ int part[256];
    int tid = threadIdx.x;
    int v[4]; int sum = 0;
#pragma unroll
    for (int k = 0; k < 4; ++k) {
        int i = tid * 4 + k;
        v[k] = (i < NB) ? bCnt[i] : 0;
        sum += v[k];
    }
    part[tid] = sum; __syncthreads();
    for (int off = 1; off < 256; off <<= 1) {
        int t = (tid >= off) ? part[tid - off] : 0;
        __syncthreads();
        part[tid] += t;
        __syncthreads();
    }
    int base = part[tid] - sum;   // exclusive
#pragma unroll
    for (int k = 0; k < 4; ++k) {
        int i = tid * 4 + k;
        if (i < NB) { bBase[i] = base; bCur[i] = base; }
        base += v[k];
    }
    if (tid == 255) bBase[NB] = E;
}

// ---------------- partition edges into 128-node dst buckets (packed: src<<7 | dst&127) ------
__global__ __launch_bounds__(256) void partition(const int* __restrict__ src,
                                                 const int* __restrict__ dst,
                                                 int* __restrict__ bCur,
                                                 int* __restrict__ pkBuf, int E, int NB) {
    __shared__ int hcnt[MAXNB];
    __shared__ int hbase[MAXNB];
    int tid = threadIdx.x;
    for (int i = tid; i < NB; i += 256) hcnt[i] = 0;
    __syncthreads();
    int e0 = blockIdx.x * PCHUNK;
    int eend = e0 + PCHUNK; if (eend > E) eend = E;
    for (int e = e0 + tid; e < eend; e += 256)      // pass 1: count (dst read 1)
        atomicAdd(&hcnt[dst[e] >> 7], 1);
    __syncthreads();
    for (int b = tid; b < NB; b += 256) {
        int c = hcnt[b];
        hbase[b] = c ? atomicAdd(&bCur[b], c) : 0;
        hcnt[b] = 0;
    }
    __syncthreads();
    for (int e = e0 + tid; e < eend; e += 256) {    // pass 2: place (dst read 2 = L2 hit)
        int s_ = src[e], d = dst[e];
        int b = d >> 7;
        int loc = atomicAdd(&hcnt[b], 1);
        pkBuf[hbase[b] + loc] = (s_ << 7) | (d & 127);
    }
}

// ---------------- per-bucket: node counts -> ptr + dinv, then exact scatter to CSR ----------
__global__ __launch_bounds__(256) void bucket_finalize(const int* __restrict__ bBase,
                                                       const int* __restrict__ pkBuf,
                                                       int* __restrict__ ptr,
                                                       float* __restrict__ dinv,
                                                       int* __restrict__ sIdx, int n, int E) {
    __shared__ int cnt128[128];
    __shared__ int sc[128];
    __shared__ int cur[128];
    int b = blockIdx.x;
    int node0 = b << 7;
    int tid = threadIdx.x;
    if (tid < 128) cnt128[tid] = 0;
    __syncthreads();
    int beg = bBase[b], end = bBase[b + 1];
    for (int j = beg + tid; j < end; j += 256)
        atomicAdd(&cnt128[pkBuf[j] & 127], 1);
    __syncthreads();
    int v = (tid < 128) ? cnt128[tid] : 0;
    if (tid < 128) sc[tid] = v;
    __syncthreads();
    for (int off = 1; off < 128; off <<= 1) {
        int t = (tid < 128 && tid >= off) ? sc[tid - off] : 0;
        __syncthreads();
        if (tid < 128) sc[tid] += t;
        __syncthreads();
    }
    if (tid < 128) {
        int node = node0 + tid;
        if (node < n) {
            int p = beg + sc[tid] - v;
            ptr[node] = p;
            cur[tid] = p;
            dinv[node] = rsqrtf((float)v + 1.0f);   // +1 self loop
        }
    }
    if (tid == 0 && b == gridDim.x - 1) ptr[n] = E;
    __syncthreads();
    for (int j = beg + tid; j < end; j += 256) {
        int p = pkBuf[j];
        int pos = atomicAdd(&cur[p & 127], 1);
        sIdx[pos] = p >> 7;
    }
}

// ---------------- layer 1 GEMM via f16 MFMA: h1 = f16(x @ W1) ----------------
#define ASTRIDE 132   // f16 row stride (128 + 4 pad)
__global__ __launch_bounds__(256) void gemm1_mfma(const float* __restrict__ x,
                                                  const float* __restrict__ W1,
                                                  _Float16* __restrict__ h1, int n) {
    __shared__ _Float16 Ah[64 * ASTRIDE];
    __shared__ _Float16 Wt[64 * ASTRIDE];
    int tid = threadIdx.x;
    int node0 = blockIdx.x * 64;
#pragma unroll
    for (int i = 0; i < 8; ++i) {
        int f = (i * 256 + tid) * 4;
        int m = f >> 7, k = f & 127;
        float4 v = (node0 + m < n) ? ((const float4*)(x + (size_t)(node0 + m) * F_IN))[k >> 2]
                                   : make_float4(0.f, 0.f, 0.f, 0.f);
        _Float16* p = &Ah[m * ASTRIDE + k];
        p[0] = (_Float16)v.x; p[1] = (_Float16)v.y; p[2] = (_Float16)v.z; p[3] = (_Float16)v.w;
    }
#pragma unroll
    for (int i = 0; i < 32; ++i) {
        int f = i * 256 + tid;              // f = k*64 + nout
        int k = f >> 6, nn = f & 63;
        Wt[nn * ASTRIDE + k] = (_Float16)W1[f];
    }
    __syncthreads();
    int wave = tid >> 6, lane = tid & 63;
    int m0 = wave * 16;
    int col = lane & 15, quad = lane >> 4;
    floatx4 acc[4] = {{0,0,0,0},{0,0,0,0},{0,0,0,0},{0,0,0,0}};
#pragma unroll
    for (int kk = 0; kk < 4; ++kk) {
        int kbase = kk * 32 + quad * 8;
        half8 a = ld_half8_u8(&Ah[(m0 + col) * ASTRIDE + kbase]);
#pragma unroll
        for (int t = 0; t < 4; ++t) {
            half8 b = ld_half8_u8(&Wt[(t * 16 + col) * ASTRIDE + kbase]);
            acc[t] = __builtin_amdgcn_mfma_f32_16x16x32_f16(a, b, acc[t], 0, 0, 0);
        }
    }
#pragma unroll
    for (int t = 0; t < 4; ++t)
#pragma unroll
        for (int r = 0; r < 4; ++r) {
            int node = node0 + m0 + quad * 4 + r;
            if (node < n) h1[(size_t)node * HID + t * 16 + col] = (_Float16)acc[t][r];
        }
}

// ---------------- shared gather core: 4 nodes/wave, 16 lanes/node (2 slots x 8 chunks) ------
// After this returns, ALL 16 lanes of the node's group hold the reduced acc[8].
__device__ __forceinline__ void gather_core(const int* __restrict__ ptr,
                                            const int* __restrict__ sIdx,
                                            const float* __restrict__ dinv,
                                            const _Float16* __restrict__ hin,
                                            int node, bool valid, int slot, int fq,
                                            float acc[8]) {
    int nodeC = valid ? node : 0;
    int beg = ptr[nodeC];
    int end = valid ? ptr[nodeC + 1] : beg;
    float di = dinv[nodeC];
    float a1[8];
#pragma unroll
    for (int j = 0; j < 8; ++j) { acc[j] = 0.f; a1[j] = 0.f; }
    if (slot == 0 && valid) {                      // self loop
        half8 v = *(const half8*)(hin + node * HID + fq * 8);
        float w = di * di;
#pragma unroll
        for (int j = 0; j < 8; ++j) acc[j] = (float)v[j] * w;
    }
    for (int j0 = beg; j0 < end; j0 += 4) {
        int ja = j0 + slot, jb = j0 + 2 + slot;
        bool va = ja < end, vb = jb < end;
        int sa = sIdx[va ? ja : beg];
        int sb = sIdx[vb ? jb : beg];
        float wa = va ? dinv[sa] * di : 0.f;
        float wb = vb ? dinv[sb] * di : 0.f;
        half8 ra = *(const half8*)(hin + sa * HID + fq * 8);   // 32-bit offsets
        half8 rb = *(const half8*)(hin + sb * HID + fq * 8);
#pragma unroll
        for (int j = 0; j < 8; ++j) {
            acc[j] = fmaf((float)ra[j], wa, acc[j]);
            a1[j]  = fmaf((float)rb[j], wb, a1[j]);
        }
    }
#pragma unroll
    for (int j = 0; j < 8; ++j) {
        acc[j] += a1[j];
        acc[j] += __shfl_xor(acc[j], 8, 64);       // combine the 2 slots
    }
}

// ---------------- layer-1 aggregation: h = relu(Ah1 + b1), f16 out ----------------
__global__ __launch_bounds__(256) void gather4n_relu(const int* __restrict__ ptr,
                                                     const int* __restrict__ sIdx,
                                                     const float* __restrict__ dinv,
                                                     const _Float16* __restrict__ hin,
                                                     const float* __restrict__ bias,
                                                     _Float16* __restrict__ hout, int n) {
    int tid = threadIdx.x, wave = tid >> 6, lane = tid & 63;
    int ng = lane >> 4, slot = (lane >> 3) & 1, fq = lane & 7;
    int node = blockIdx.x * 16 + wave * 4 + ng;
    bool valid = node < n;
    float acc[8];
    gather_core(ptr, sIdx, dinv, hin, node, valid, slot, fq, acc);
    if (slot == 0 && valid) {
        union { half8 h; uint4 u; } o;
#pragma unroll
        for (int j = 0; j < 8; ++j)
            o.h[j] = (_Float16)fmaxf(acc[j] + bias[fq * 8 + j], 0.f);
        *(uint4*)(hout + node * HID + fq * 8) = o.u;
    }
}

// ---------------- fused layer-2: g = Ah (LDS), out = log_softmax(g @ W2 + b2) ----------------
__global__ __launch_bounds__(256) void gather_gemm2_logsm(const int* __restrict__ ptr,
                                                          const int* __restrict__ sIdx,
                                                          const float* __restrict__ dinv,
                                                          const _Float16* __restrict__ hin,
                                                          const float* __restrict__ W2,
                                                          const float* __restrict__ b2,
                                                          float* __restrict__ out, int n) {
    __shared__ float Ws[HID * NCLS];   // 10 KB
    __shared__ float gbuf[16][HID];    // 4 KB
    int tid = threadIdx.x, wave = tid >> 6, lane = tid & 63;
    for (int i = tid; i < HID * NCLS; i += 256) Ws[i] = W2[i];

    int ng = lane >> 4, slot = (lane >> 3) & 1, fq = lane & 7;
    int n16 = wave * 4 + ng;
    int node = blockIdx.x * 16 + n16;
    bool valid = node < n;
    float acc[8];
    gather_core(ptr, sIdx, dinv, hin, node, valid, slot, fq, acc);
    if (slot == 0 && valid) {
        float* gp = &gbuf[n16][fq * 8];
#pragma unroll
        for (int j = 0; j < 8; ++j) gp[j] = acc[j];
    }
    __syncthreads();                   // Ws staged + gbuf visible (wave-local anyway)

    // each wave finishes its own 4 nodes: 64x40 matvec + log_softmax
    for (int q = 0; q < 4; ++q) {
        int nd = blockIdx.x * 16 + wave * 4 + q;
        bool act = (lane < NCLS) && (nd < n);
        float a = -INFINITY;
        if (act) {
            a = b2[lane];
            const float* gr = gbuf[wave * 4 + q];
#pragma unroll
            for (int k = 0; k < HID; ++k) a = fmaf(gr[k], Ws[k * NCLS + lane], a);
        }
        float m = a;
        for (int off = 32; off; off >>= 1) m = fmaxf(m, __shfl_xor(m, off, 64));
        float ex = act ? expf(a - m) : 0.f;
        float s = ex;
        for (int off = 32; off; off >>= 1) s += __shfl_xor(s, off, 64);
        if (act) out[nd * NCLS + lane] = a - m - logf(s);
    }
}

extern "C" void kernel_launch(void* const* d_in, const int* in_sizes, int n_in,
                              void* d_out, int out_size, void* d_ws, size_t ws_size,
                              hipStream_t stream) {
    const float* x  = (const float*)d_in[0];
    const int*   ei = (const int*)d_in[1];
    const float* W1 = (const float*)d_in[2];
    const float* b1 = (const float*)d_in[3];
    const float* W2 = (const float*)d_in[4];
    const float* b2 = (const float*)d_in[5];
    float* out = (float*)d_out;

    int n = in_sizes[0] / F_IN;        // 100000
    int E = in_sizes[1] / 2;           // 3200000
    const int* src = ei;
    const int* dst = ei + E;
    int NB = (n + 127) >> 7;           // 782 dst buckets

    // workspace layout
    char* ws = (char*)d_ws;
    const size_t MB = 1024 * 1024;
    int*      bCnt  = (int*)  (ws);                      // NB ints
    int*      bBase = (int*)  (ws + 64 * 1024);          // NB+1 ints
    int*      bCur  = (int*)  (ws + 128 * 1024);         // NB ints
    int*      ptr   = (int*)  (ws + 192 * 1024);         // n+1 ints
    float*    dinv  = (float*)(ws + 1 * MB);             // n floats
    int*      sIdx  = (int*)     (ws + 2 * MB);          // E ints  (13 MB)
    int*      pkBuf = (int*)     (ws + 15 * MB);         // E ints  (13 MB)
    _Float16* bufA  = (_Float16*)(ws + 28 * MB);         // n*64 f16: h1
    _Float16* bufB  = (_Float16*)(ws + 41 * MB);         // n*64 f16: h

    hipMemsetAsync(bCnt, 0, (size_t)NB * sizeof(int), stream);
    bucket_histo<<<(E + HCHUNK - 1) / HCHUNK, 256, 0, stream>>>(dst, E, bCnt, NB);
    scan_buckets<<<1, 256, 0, stream>>>(bCnt, bBase, bCur, NB, E);
    partition<<<(E + PCHUNK - 1) / PCHUNK, 256, 0, stream>>>(src, dst, bCur, pkBuf, E, NB);
    bucket_finalize<<<NB, 256, 0, stream>>>(bBase, pkBuf, ptr, dinv, sIdx, n, E);

    gemm1_mfma<<<(n + 63) / 64, 256, 0, stream>>>(x, W1, bufA, n);
    gather4n_relu<<<(n + 15) / 16, 256, 0, stream>>>(ptr, sIdx, dinv, bufA, b1, bufB, n);
    gather_gemm2_logsm<<<(n + 15) / 16, 256, 0, stream>>>(ptr, sIdx, dinv, bufB, W2, b2, out, n);
}

// Round 8
// 366.599 us; speedup vs baseline: 1.1610x; 1.1610x over previous
//
#include <hip/hip_runtime.h>
#include <math.h>

#define F_IN 128
#define HID  64
#define NCLS 40
#define HCHUNK 4096
#define PART_CHUNK 4096
#define MAXNB 1024

typedef _Float16 half8 __attribute__((ext_vector_type(8)));
typedef float floatx4 __attribute__((ext_vector_type(4)));

// load 8 f16 from an 8B-aligned (not necessarily 16B) pointer (LDS staging use)
__device__ inline half8 ld_half8_u8(const _Float16* p) {
    union { uint2 u[2]; half8 h; } r;
    r.u[0] = *(const uint2*)p;
    r.u[1] = *(const uint2*)(p + 4);
    return r.h;
}

// ---------------- bucket-level histogram (LDS-privatized, 782 bins) ----------------
__global__ __launch_bounds__(256) void bucket_histo(const int* __restrict__ dst, int E,
                                                    int* __restrict__ bCnt, int NB) {
    __shared__ int h[MAXNB];
    int tid = threadIdx.x;
    for (int i = tid; i < NB; i += 256) h[i] = 0;
    __syncthreads();
    int e0 = blockIdx.x * HCHUNK;
    int eend = e0 + HCHUNK; if (eend > E) eend = E;
    for (int e = e0 + tid; e < eend; e += 256)
        atomicAdd(&h[dst[e] >> 7], 1);
    __syncthreads();
    for (int b = tid; b < NB; b += 256) {
        int c = h[b];
        if (c) atomicAdd(&bCnt[b], c);
    }
}

// ---------------- single-block exclusive scan of bucket counts ----------------
__global__ __launch_bounds__(256) void scan_buckets(const int* __restrict__ bCnt,
                                                    int* __restrict__ bBase,
                                                    int* __restrict__ bCur, int NB, int E) {
    __shared__ int part[256];
    int tid = threadIdx.x;
    int v[4]; int sum = 0;
#pragma unroll
    for (int k = 0; k < 4; ++k) {
        int i = tid * 4 + k;
        v[k] = (i < NB) ? bCnt[i] : 0;
        sum += v[k];
    }
    part[tid] = sum; __syncthreads();
    for (int off = 1; off < 256; off <<= 1) {
        int t = (tid >= off) ? part[tid - off] : 0;
        __syncthreads();
        part[tid] += t;
        __syncthreads();
    }
    int base = part[tid] - sum;   // exclusive
#pragma unroll
    for (int k = 0; k < 4; ++k) {
        int i = tid * 4 + k;
        if (i < NB) { bBase[i] = base; bCur[i] = base; }
        base += v[k];
    }
    if (tid == 255) bBase[NB] = E;
}

// ---------------- partition edges into 128-node dst buckets (packed: src<<7 | dst&127) ------
__global__ __launch_bounds__(256) void partition(const int* __restrict__ src,
                                                 const int* __restrict__ dst,
                                                 int* __restrict__ bCur,
                                                 int* __restrict__ pkBuf, int E, int NB) {
    __shared__ int hcnt[MAXNB];
    __shared__ int hbase[MAXNB];
    int tid = threadIdx.x;
    for (int i = tid; i < NB; i += 256) hcnt[i] = 0;
    __syncthreads();
    int e0 = blockIdx.x * PART_CHUNK;
    int s_[16], d_[16];
#pragma unroll
    for (int i = 0; i < 16; ++i) {
        int e = e0 + i * 256 + tid;
        if (e < E) {
            s_[i] = src[e]; d_[i] = dst[e];
            atomicAdd(&hcnt[d_[i] >> 7], 1);
        }
    }
    __syncthreads();
    for (int b = tid; b < NB; b += 256) {
        int c = hcnt[b];
        hbase[b] = c ? atomicAdd(&bCur[b], c) : 0;
        hcnt[b] = 0;
    }
    __syncthreads();
#pragma unroll
    for (int i = 0; i < 16; ++i) {
        int e = e0 + i * 256 + tid;
        if (e < E) {
            int b = d_[i] >> 7;
            int loc = atomicAdd(&hcnt[b], 1);
            pkBuf[hbase[b] + loc] = (s_[i] << 7) | (d_[i] & 127);
        }
    }
}

// ---------------- per-bucket: node counts -> ptr + dinv, then exact scatter to CSR ----------
__global__ __launch_bounds__(256) void bucket_finalize(const int* __restrict__ bBase,
                                                       const int* __restrict__ pkBuf,
                                                       int* __restrict__ ptr,
                                                       float* __restrict__ dinv,
                                                       int* __restrict__ sIdx, int n, int E) {
    __shared__ int cnt128[128];
    __shared__ int sc[128];
    __shared__ int cur[128];
    int b = blockIdx.x;
    int node0 = b << 7;
    int tid = threadIdx.x;
    if (tid < 128) cnt128[tid] = 0;
    __syncthreads();
    int beg = bBase[b], end = bBase[b + 1];
    for (int j = beg + tid; j < end; j += 256)
        atomicAdd(&cnt128[pkBuf[j] & 127], 1);
    __syncthreads();
    int v = (tid < 128) ? cnt128[tid] : 0;
    if (tid < 128) sc[tid] = v;
    __syncthreads();
    for (int off = 1; off < 128; off <<= 1) {
        int t = (tid < 128 && tid >= off) ? sc[tid - off] : 0;
        __syncthreads();
        if (tid < 128) sc[tid] += t;
        __syncthreads();
    }
    if (tid < 128) {
        int node = node0 + tid;
        if (node < n) {
            int p = beg + sc[tid] - v;
            ptr[node] = p;
            cur[tid] = p;
            dinv[node] = rsqrtf((float)v + 1.0f);   // +1 self loop
        }
    }
    if (tid == 0 && b == gridDim.x - 1) ptr[n] = E;
    __syncthreads();
    for (int j = beg + tid; j < end; j += 256) {
        int p = pkBuf[j];
        int pos = atomicAdd(&cur[p & 127], 1);
        sIdx[pos] = p >> 7;
    }
}

// ---------------- layer 1 GEMM via f16 MFMA: h1 = f16(x @ W1) ----------------
#define ASTRIDE 132   // f16 row stride (128 + 4 pad)
__global__ __launch_bounds__(256) void gemm1_mfma(const float* __restrict__ x,
                                                  const float* __restrict__ W1,
                                                  _Float16* __restrict__ h1, int n) {
    __shared__ _Float16 Ah[64 * ASTRIDE];
    __shared__ _Float16 Wt[64 * ASTRIDE];
    int tid = threadIdx.x;
    int node0 = blockIdx.x * 64;
#pragma unroll
    for (int i = 0; i < 8; ++i) {          // 8*256*4 = 8192 floats = 64 rows x 128 cols
        int f = (i * 256 + tid) * 4;
        int m = f >> 7, k = f & 127;
        float4 v = (node0 + m < n) ? ((const float4*)(x + (size_t)(node0 + m) * F_IN))[k >> 2]
                                   : make_float4(0.f, 0.f, 0.f, 0.f);
        _Float16* p = &Ah[m * ASTRIDE + k];
        p[0] = (_Float16)v.x; p[1] = (_Float16)v.y; p[2] = (_Float16)v.z; p[3] = (_Float16)v.w;
    }
#pragma unroll
    for (int i = 0; i < 32; ++i) {
        int f = i * 256 + tid;              // f = k*64 + nout
        int k = f >> 6, nn = f & 63;
        Wt[nn * ASTRIDE + k] = (_Float16)W1[f];
    }
    __syncthreads();
    int wave = tid >> 6, lane = tid & 63;
    int m0 = wave * 16;
    int col = lane & 15, quad = lane >> 4;
    floatx4 acc[4] = {{0,0,0,0},{0,0,0,0},{0,0,0,0},{0,0,0,0}};
#pragma unroll
    for (int kk = 0; kk < 4; ++kk) {
        int kbase = kk * 32 + quad * 8;
        half8 a = ld_half8_u8(&Ah[(m0 + col) * ASTRIDE + kbase]);
#pragma unroll
        for (int t = 0; t < 4; ++t) {
            half8 b = ld_half8_u8(&Wt[(t * 16 + col) * ASTRIDE + kbase]);
            acc[t] = __builtin_amdgcn_mfma_f32_16x16x32_f16(a, b, acc[t], 0, 0, 0);
        }
    }
#pragma unroll
    for (int t = 0; t < 4; ++t)
#pragma unroll
        for (int r = 0; r < 4; ++r) {
            int node = node0 + m0 + quad * 4 + r;
            if (node < n) h1[(size_t)node * HID + t * 16 + col] = (_Float16)acc[t][r];
        }
}

// ---------------- CSR gather on f16 rows: wave/node, 8 lanes/edge, 16 edges/iter ----------
template<bool RELU>
__global__ __launch_bounds__(256) void gather16(const int* __restrict__ ptr,
                                                const int* __restrict__ sIdx,
                                                const float* __restrict__ dinv,
                                                const _Float16* __restrict__ hin,
                                                const float* __restrict__ bias,
                                                _Float16* __restrict__ hout, int n) {
    int tid = threadIdx.x, lane = tid & 63;
    int node = blockIdx.x * 4 + (tid >> 6);
    if (node >= n) return;
    int grp = lane >> 3;          // edge slot 0..7
    int fq  = lane & 7;           // 16B chunk within 128B row
    int beg = ptr[node], end = ptr[node + 1];
    float di = dinv[node];
    float a0[8] = {0,0,0,0,0,0,0,0}, a1[8] = {0,0,0,0,0,0,0,0};

    if (grp == 0) {               // self loop
        half8 v = *(const half8*)(hin + (size_t)node * HID + fq * 8);
        float w = di * di;
#pragma unroll
        for (int j = 0; j < 8; ++j) a0[j] = (float)v[j] * w;
    }
    for (int j0 = beg; j0 < end; j0 += 16) {
        int ja = j0 + grp, jb = j0 + 8 + grp;
        bool va = ja < end, vb = jb < end;
        int sa = sIdx[va ? ja : beg];
        int sb = sIdx[vb ? jb : beg];
        float wa = va ? dinv[sa] * di : 0.f;
        float wb = vb ? dinv[sb] * di : 0.f;
        half8 ra = *(const half8*)(hin + (size_t)sa * HID + fq * 8);
        half8 rb = *(const half8*)(hin + (size_t)sb * HID + fq * 8);
#pragma unroll
        for (int j = 0; j < 8; ++j) {
            a0[j] = fmaf((float)ra[j], wa, a0[j]);
            a1[j] = fmaf((float)rb[j], wb, a1[j]);
        }
    }
#pragma unroll
    for (int j = 0; j < 8; ++j) a0[j] += a1[j];
#pragma unroll
    for (int off = 8; off < 64; off <<= 1)
#pragma unroll
        for (int j = 0; j < 8; ++j) a0[j] += __shfl_xor(a0[j], off, 64);
    if (grp == 0) {
        union { half8 h; uint4 u; } o;
#pragma unroll
        for (int j = 0; j < 8; ++j) {
            float v = a0[j];
            if (RELU) v = fmaxf(v + bias[fq * 8 + j], 0.f);
            o.h[j] = (_Float16)v;
        }
        *(uint4*)(hout + (size_t)node * HID + fq * 8) = o.u;
    }
}

// ---------------- out = log_softmax(g @ W2 + b2) via MFMA, 64 nodes/block ----------------
#define GSTRIDE 72    // f16 row stride (64 + 8 pad)
__global__ __launch_bounds__(256) void gemm2_mfma_logsm(const _Float16* __restrict__ g,
                                                        const float* __restrict__ W2,
                                                        const float* __restrict__ b2,
                                                        float* __restrict__ out, int n) {
    __shared__ _Float16 gt[64 * GSTRIDE];   // 9216 B
    __shared__ _Float16 wt[48 * GSTRIDE];   // 6912 B, W2^T zero-padded to 48 cols
    int tid = threadIdx.x;
    int node0 = blockIdx.x * 64;
#pragma unroll
    for (int i = 0; i < 2; ++i) {           // 2*256*8 = 4096 f16 = 64 rows x 64 cols EXACTLY
        int f = (i * 256 + tid) * 8;
        int m = f >> 6, k = f & 63;
        union { uint4 u; half8 h; } v;
        if (node0 + m < n) v.u = *(const uint4*)(g + (size_t)(node0 + m) * HID + k);
        else v.u = make_uint4(0, 0, 0, 0);
        *(uint4*)&gt[m * GSTRIDE + k] = v.u;
    }
#pragma unroll
    for (int i = 0; i < 12; ++i) {          // stage W2^T (f32 -> f16), 3072 elems
        int f = i * 256 + tid;              // f = c*64 + k
        int c = f >> 6, k = f & 63;
        wt[c * GSTRIDE + k] = (c < NCLS) ? (_Float16)W2[k * NCLS + c] : (_Float16)0.f;
    }
    __syncthreads();

    int wave = tid >> 6, lane = tid & 63;
    int m0 = wave * 16;
    int col = lane & 15, quad = lane >> 4;
    floatx4 acc[3] = {{0,0,0,0},{0,0,0,0},{0,0,0,0}};
#pragma unroll
    for (int kk = 0; kk < 2; ++kk) {
        int kbase = kk * 32 + quad * 8;
        half8 a = *(const half8*)&gt[(m0 + col) * GSTRIDE + kbase];   // A[m=col][k]
#pragma unroll
        for (int t = 0; t < 3; ++t) {
            half8 b = *(const half8*)&wt[(t * 16 + col) * GSTRIDE + kbase]; // B[k][c=col]
            acc[t] = __builtin_amdgcn_mfma_f32_16x16x32_f16(a, b, acc[t], 0, 0, 0);
        }
    }
    // epilogue: per row (node) max/sum across the 16 lanes of this quad, 3 col-tiles
    float bb[3];
#pragma unroll
    for (int t = 0; t < 3; ++t) {
        int c = t * 16 + col;
        bb[t] = (c < NCLS) ? b2[c] : 0.f;
    }
#pragma unroll
    for (int r = 0; r < 4; ++r) {
        int node = node0 + m0 + quad * 4 + r;
        float v0 = acc[0][r] + bb[0];
        float v1 = acc[1][r] + bb[1];
        float v2 = (col < 8) ? acc[2][r] + bb[2] : -INFINITY;
        float m = fmaxf(fmaxf(v0, v1), v2);
#pragma unroll
        for (int off = 1; off < 16; off <<= 1) m = fmaxf(m, __shfl_xor(m, off, 64));
        float s = expf(v0 - m) + expf(v1 - m) + ((col < 8) ? expf(v2 - m) : 0.f);
#pragma unroll
        for (int off = 1; off < 16; off <<= 1) s += __shfl_xor(s, off, 64);
        float ls = logf(s);
        if (node < n) {
            float* op = out + (size_t)node * NCLS;
            op[col]      = v0 - m - ls;
            op[16 + col] = v1 - m - ls;
            if (col < 8) op[32 + col] = v2 - m - ls;
        }
    }
}

extern "C" void kernel_launch(void* const* d_in, const int* in_sizes, int n_in,
                              void* d_out, int out_size, void* d_ws, size_t ws_size,
                              hipStream_t stream) {
    const float* x  = (const float*)d_in[0];
    const int*   ei = (const int*)d_in[1];
    const float* W1 = (const float*)d_in[2];
    const float* b1 = (const float*)d_in[3];
    const float* W2 = (const float*)d_in[4];
    const float* b2 = (const float*)d_in[5];
    float* out = (float*)d_out;

    int n = in_sizes[0] / F_IN;        // 100000
    int E = in_sizes[1] / 2;           // 3200000
    const int* src = ei;
    const int* dst = ei + E;
    int NB = (n + 127) >> 7;           // 782 dst buckets

    // workspace layout
    char* ws = (char*)d_ws;
    const size_t MB = 1024 * 1024;
    int*      bCnt  = (int*)  (ws);                      // NB ints
    int*      bBase = (int*)  (ws + 64 * 1024);          // NB+1 ints
    int*      bCur  = (int*)  (ws + 128 * 1024);         // NB ints
    int*      ptr   = (int*)  (ws + 192 * 1024);         // n+1 ints
    float*    dinv  = (float*)(ws + 1 * MB);             // n floats
    int*      sIdx  = (int*)     (ws + 2 * MB);          // E ints  (13 MB)
    int*      pkBuf = (int*)     (ws + 15 * MB);         // E ints  (13 MB)
    _Float16* bufA  = (_Float16*)(ws + 28 * MB);         // n*64 f16: h1, later g
    _Float16* bufB  = (_Float16*)(ws + 41 * MB);         // n*64 f16: h

    hipMemsetAsync(bCnt, 0, (size_t)NB * sizeof(int), stream);
    bucket_histo<<<(E + HCHUNK - 1) / HCHUNK, 256, 0, stream>>>(dst, E, bCnt, NB);
    scan_buckets<<<1, 256, 0, stream>>>(bCnt, bBase, bCur, NB, E);
    partition<<<(E + PART_CHUNK - 1) / PART_CHUNK, 256, 0, stream>>>(src, dst, bCur, pkBuf, E, NB);
    bucket_finalize<<<NB, 256, 0, stream>>>(bBase, pkBuf, ptr, dinv, sIdx, n, E);

    gemm1_mfma<<<(n + 63) / 64, 256, 0, stream>>>(x, W1, bufA, n);
    gather16<true ><<<(n + 3) / 4, 256, 0, stream>>>(ptr, sIdx, dinv, bufA, b1, bufB, n); // h
    gather16<false><<<(n + 3) / 4, 256, 0, stream>>>(ptr, sIdx, dinv, bufB, b1, bufA, n); // g
    gemm2_mfma_logsm<<<(n + 63) / 64, 256, 0, stream>>>(bufA, W2, b2, out, n);
}

// Round 9
// 363.486 us; speedup vs baseline: 1.1709x; 1.0086x over previous
//
#include <hip/hip_runtime.h>
#include <math.h>

#define F_IN 128
#define HID  64
#define NCLS 40
#define HCHUNK 4096
#define PART_CHUNK 4096
#define MAXNB 1024

typedef _Float16 half8 __attribute__((ext_vector_type(8)));
typedef _Float16 half2t __attribute__((ext_vector_type(2)));
typedef float floatx4 __attribute__((ext_vector_type(4)));

// load 8 f16 from an 8B-aligned (not necessarily 16B) pointer (LDS staging use)
__device__ inline half8 ld_half8_u8(const _Float16* p) {
    union { uint2 u[2]; half8 h; } r;
    r.u[0] = *(const uint2*)p;
    r.u[1] = *(const uint2*)(p + 4);
    return r.h;
}

// ---------------- bucket-level histogram (LDS-privatized, 782 bins) ----------------
__global__ __launch_bounds__(256) void bucket_histo(const int* __restrict__ dst, int E,
                                                    int* __restrict__ bCnt, int NB) {
    __shared__ int h[MAXNB];
    int tid = threadIdx.x;
    for (int i = tid; i < NB; i += 256) h[i] = 0;
    __syncthreads();
    int e0 = blockIdx.x * HCHUNK;
    int eend = e0 + HCHUNK; if (eend > E) eend = E;
    for (int e = e0 + tid; e < eend; e += 256)
        atomicAdd(&h[dst[e] >> 7], 1);
    __syncthreads();
    for (int b = tid; b < NB; b += 256) {
        int c = h[b];
        if (c) atomicAdd(&bCnt[b], c);
    }
}

// ---------------- single-block exclusive scan of bucket counts ----------------
__global__ __launch_bounds__(256) void scan_buckets(const int* __restrict__ bCnt,
                                                    int* __restrict__ bBase,
                                                    int* __restrict__ bCur, int NB, int E) {
    __shared__ int part[256];
    int tid = threadIdx.x;
    int v[4]; int sum = 0;
#pragma unroll
    for (int k = 0; k < 4; ++k) {
        int i = tid * 4 + k;
        v[k] = (i < NB) ? bCnt[i] : 0;
        sum += v[k];
    }
    part[tid] = sum; __syncthreads();
    for (int off = 1; off < 256; off <<= 1) {
        int t = (tid >= off) ? part[tid - off] : 0;
        __syncthreads();
        part[tid] += t;
        __syncthreads();
    }
    int base = part[tid] - sum;   // exclusive
#pragma unroll
    for (int k = 0; k < 4; ++k) {
        int i = tid * 4 + k;
        if (i < NB) { bBase[i] = base; bCur[i] = base; }
        base += v[k];
    }
    if (tid == 255) bBase[NB] = E;
}

// ---------------- partition edges into 128-node dst buckets (packed: src<<7 | dst&127) ------
__global__ __launch_bounds__(256) void partition(const int* __restrict__ src,
                                                 const int* __restrict__ dst,
                                                 int* __restrict__ bCur,
                                                 int* __restrict__ pkBuf, int E, int NB) {
    __shared__ int hcnt[MAXNB];
    __shared__ int hbase[MAXNB];
    int tid = threadIdx.x;
    for (int i = tid; i < NB; i += 256) hcnt[i] = 0;
    __syncthreads();
    int e0 = blockIdx.x * PART_CHUNK;
    int s_[16], d_[16];
#pragma unroll
    for (int i = 0; i < 16; ++i) {
        int e = e0 + i * 256 + tid;
        if (e < E) {
            s_[i] = src[e]; d_[i] = dst[e];
            atomicAdd(&hcnt[d_[i] >> 7], 1);
        }
    }
    __syncthreads();
    for (int b = tid; b < NB; b += 256) {
        int c = hcnt[b];
        hbase[b] = c ? atomicAdd(&bCur[b], c) : 0;
        hcnt[b] = 0;
    }
    __syncthreads();
#pragma unroll
    for (int i = 0; i < 16; ++i) {
        int e = e0 + i * 256 + tid;
        if (e < E) {
            int b = d_[i] >> 7;
            int loc = atomicAdd(&hcnt[b], 1);
            pkBuf[hbase[b] + loc] = (s_[i] << 7) | (d_[i] & 127);
        }
    }
}

// ---------------- per-bucket: node counts -> ptr + dinv, then exact scatter to CSR ----------
__global__ __launch_bounds__(256) void bucket_finalize(const int* __restrict__ bBase,
                                                       const int* __restrict__ pkBuf,
                                                       int* __restrict__ ptr,
                                                       float* __restrict__ dinv,
                                                       int* __restrict__ sIdx, int n, int E) {
    __shared__ int cnt128[128];
    __shared__ int sc[128];
    __shared__ int cur[128];
    int b = blockIdx.x;
    int node0 = b << 7;
    int tid = threadIdx.x;
    if (tid < 128) cnt128[tid] = 0;
    __syncthreads();
    int beg = bBase[b], end = bBase[b + 1];
    for (int j = beg + tid; j < end; j += 256)
        atomicAdd(&cnt128[pkBuf[j] & 127], 1);
    __syncthreads();
    int v = (tid < 128) ? cnt128[tid] : 0;
    if (tid < 128) sc[tid] = v;
    __syncthreads();
    for (int off = 1; off < 128; off <<= 1) {
        int t = (tid < 128 && tid >= off) ? sc[tid - off] : 0;
        __syncthreads();
        if (tid < 128) sc[tid] += t;
        __syncthreads();
    }
    if (tid < 128) {
        int node = node0 + tid;
        if (node < n) {
            int p = beg + sc[tid] - v;
            ptr[node] = p;
            cur[tid] = p;
            dinv[node] = rsqrtf((float)v + 1.0f);   // +1 self loop
        }
    }
    if (tid == 0 && b == gridDim.x - 1) ptr[n] = E;
    __syncthreads();
    for (int j = beg + tid; j < end; j += 256) {
        int p = pkBuf[j];
        int pos = atomicAdd(&cur[p & 127], 1);
        sIdx[pos] = p >> 7;
    }
}

// ---------------- layer 1 GEMM via f16 MFMA: h1 = f16(x @ W1) ----------------
#define ASTRIDE 132   // f16 row stride (128 + 4 pad)
__global__ __launch_bounds__(256) void gemm1_mfma(const float* __restrict__ x,
                                                  const float* __restrict__ W1,
                                                  _Float16* __restrict__ h1, int n) {
    __shared__ _Float16 Ah[64 * ASTRIDE];
    __shared__ _Float16 Wt[64 * ASTRIDE];
    int tid = threadIdx.x;
    int node0 = blockIdx.x * 64;
#pragma unroll
    for (int i = 0; i < 8; ++i) {          // 8*256*4 = 8192 floats = 64 rows x 128 cols
        int f = (i * 256 + tid) * 4;
        int m = f >> 7, k = f & 127;
        float4 v = (node0 + m < n) ? ((const float4*)(x + (size_t)(node0 + m) * F_IN))[k >> 2]
                                   : make_float4(0.f, 0.f, 0.f, 0.f);
        _Float16* p = &Ah[m * ASTRIDE + k];
        p[0] = (_Float16)v.x; p[1] = (_Float16)v.y; p[2] = (_Float16)v.z; p[3] = (_Float16)v.w;
    }
#pragma unroll
    for (int i = 0; i < 32; ++i) {
        int f = i * 256 + tid;              // f = k*64 + nout
        int k = f >> 6, nn = f & 63;
        Wt[nn * ASTRIDE + k] = (_Float16)W1[f];
    }
    __syncthreads();
    int wave = tid >> 6, lane = tid & 63;
    int m0 = wave * 16;
    int col = lane & 15, quad = lane >> 4;
    floatx4 acc[4] = {{0,0,0,0},{0,0,0,0},{0,0,0,0},{0,0,0,0}};
#pragma unroll
    for (int kk = 0; kk < 4; ++kk) {
        int kbase = kk * 32 + quad * 8;
        half8 a = ld_half8_u8(&Ah[(m0 + col) * ASTRIDE + kbase]);
#pragma unroll
        for (int t = 0; t < 4; ++t) {
            half8 b = ld_half8_u8(&Wt[(t * 16 + col) * ASTRIDE + kbase]);
            acc[t] = __builtin_amdgcn_mfma_f32_16x16x32_f16(a, b, acc[t], 0, 0, 0);
        }
    }
#pragma unroll
    for (int t = 0; t < 4; ++t)
#pragma unroll
        for (int r = 0; r < 4; ++r) {
            int node = node0 + m0 + quad * 4 + r;
            if (node < n) h1[(size_t)node * HID + t * 16 + col] = (_Float16)acc[t][r];
        }
}

// ---------------- CSR gather on f16 rows: wave/node, 8 lanes/edge, 16 edges/iter ----------
// Inner accumulate via v_dot2_f32_f16: pairs the two edge slots elementwise, f32 acc.
template<bool RELU>
__global__ __launch_bounds__(256) void gather16(const int* __restrict__ ptr,
                                                const int* __restrict__ sIdx,
                                                const float* __restrict__ dinv,
                                                const _Float16* __restrict__ hin,
                                                const float* __restrict__ bias,
                                                _Float16* __restrict__ hout, int n) {
    int tid = threadIdx.x, lane = tid & 63;
    int node = blockIdx.x * 4 + (tid >> 6);
    if (node >= n) return;
    int grp = lane >> 3;          // edge slot 0..7
    int fq  = lane & 7;           // 16B chunk within 128B row
    int beg = ptr[node], end = ptr[node + 1];
    float di = dinv[node];
    float a0[8] = {0,0,0,0,0,0,0,0};

    if (grp == 0) {               // self loop
        half8 v = *(const half8*)(hin + (size_t)node * HID + fq * 8);
        float w = di * di;
#pragma unroll
        for (int j = 0; j < 8; ++j) a0[j] = (float)v[j] * w;
    }
    for (int j0 = beg; j0 < end; j0 += 16) {
        int ja = j0 + grp, jb = j0 + 8 + grp;
        bool va = ja < end, vb = jb < end;
        int sa = sIdx[va ? ja : beg];
        int sb = sIdx[vb ? jb : beg];
        float wa = va ? dinv[sa] * di : 0.f;
        float wb = vb ? dinv[sb] * di : 0.f;
        half8 ra = *(const half8*)(hin + (size_t)sa * HID + fq * 8);
        half8 rb = *(const half8*)(hin + (size_t)sb * HID + fq * 8);
#if __has_builtin(__builtin_amdgcn_fdot2)
        half2t wab = { (_Float16)wa, (_Float16)wb };
#pragma unroll
        for (int j = 0; j < 8; ++j) {
            half2t p = { ra[j], rb[j] };
            a0[j] = __builtin_amdgcn_fdot2(p, wab, a0[j], false);
        }
#else
#pragma unroll
        for (int j = 0; j < 8; ++j) {
            a0[j] = fmaf((float)ra[j], wa, a0[j]);
            a0[j] = fmaf((float)rb[j], wb, a0[j]);
        }
#endif
    }
#pragma unroll
    for (int off = 8; off < 64; off <<= 1)
#pragma unroll
        for (int j = 0; j < 8; ++j) a0[j] += __shfl_xor(a0[j], off, 64);
    if (grp == 0) {
        union { half8 h; uint4 u; } o;
#pragma unroll
        for (int j = 0; j < 8; ++j) {
            float v = a0[j];
            if (RELU) v = fmaxf(v + bias[fq * 8 + j], 0.f);
            o.h[j] = (_Float16)v;
        }
        *(uint4*)(hout + (size_t)node * HID + fq * 8) = o.u;
    }
}

// ---------------- out = log_softmax(g @ W2 + b2) via MFMA, 64 nodes/block ----------------
#define GSTRIDE 72    // f16 row stride (64 + 8 pad)
__global__ __launch_bounds__(256) void gemm2_mfma_logsm(const _Float16* __restrict__ g,
                                                        const float* __restrict__ W2,
                                                        const float* __restrict__ b2,
                                                        float* __restrict__ out, int n) {
    __shared__ _Float16 gt[64 * GSTRIDE];   // 9216 B
    __shared__ _Float16 wt[48 * GSTRIDE];   // 6912 B, W2^T zero-padded to 48 cols
    int tid = threadIdx.x;
    int node0 = blockIdx.x * 64;
#pragma unroll
    for (int i = 0; i < 2; ++i) {           // 2*256*8 = 4096 f16 = 64 rows x 64 cols EXACTLY
        int f = (i * 256 + tid) * 8;
        int m = f >> 6, k = f & 63;
        union { uint4 u; half8 h; } v;
        if (node0 + m < n) v.u = *(const uint4*)(g + (size_t)(node0 + m) * HID + k);
        else v.u = make_uint4(0, 0, 0, 0);
        *(uint4*)&gt[m * GSTRIDE + k] = v.u;
    }
#pragma unroll
    for (int i = 0; i < 12; ++i) {          // stage W2^T (f32 -> f16), 3072 elems
        int f = i * 256 + tid;              // f = c*64 + k
        int c = f >> 6, k = f & 63;
        wt[c * GSTRIDE + k] = (c < NCLS) ? (_Float16)W2[k * NCLS + c] : (_Float16)0.f;
    }
    __syncthreads();

    int wave = tid >> 6, lane = tid & 63;
    int m0 = wave * 16;
    int col = lane & 15, quad = lane >> 4;
    floatx4 acc[3] = {{0,0,0,0},{0,0,0,0},{0,0,0,0}};
#pragma unroll
    for (int kk = 0; kk < 2; ++kk) {
        int kbase = kk * 32 + quad * 8;
        half8 a = *(const half8*)&gt[(m0 + col) * GSTRIDE + kbase];   // A[m=col][k]
#pragma unroll
        for (int t = 0; t < 3; ++t) {
            half8 b = *(const half8*)&wt[(t * 16 + col) * GSTRIDE + kbase]; // B[k][c=col]
            acc[t] = __builtin_amdgcn_mfma_f32_16x16x32_f16(a, b, acc[t], 0, 0, 0);
        }
    }
    // epilogue: per row (node) max/sum across the 16 lanes of this quad, 3 col-tiles
    float bb[3];
#pragma unroll
    for (int t = 0; t < 3; ++t) {
        int c = t * 16 + col;
        bb[t] = (c < NCLS) ? b2[c] : 0.f;
    }
#pragma unroll
    for (int r = 0; r < 4; ++r) {
        int node = node0 + m0 + quad * 4 + r;
        float v0 = acc[0][r] + bb[0];
        float v1 = acc[1][r] + bb[1];
        float v2 = (col < 8) ? acc[2][r] + bb[2] : -INFINITY;
        float m = fmaxf(fmaxf(v0, v1), v2);
#pragma unroll
        for (int off = 1; off < 16; off <<= 1) m = fmaxf(m, __shfl_xor(m, off, 64));
        float s = expf(v0 - m) + expf(v1 - m) + ((col < 8) ? expf(v2 - m) : 0.f);
#pragma unroll
        for (int off = 1; off < 16; off <<= 1) s += __shfl_xor(s, off, 64);
        float ls = logf(s);
        if (node < n) {
            float* op = out + (size_t)node * NCLS;
            op[col]      = v0 - m - ls;
            op[16 + col] = v1 - m - ls;
            if (col < 8) op[32 + col] = v2 - m - ls;
        }
    }
}

extern "C" void kernel_launch(void* const* d_in, const int* in_sizes, int n_in,
                              void* d_out, int out_size, void* d_ws, size_t ws_size,
                              hipStream_t stream) {
    const float* x  = (const float*)d_in[0];
    const int*   ei = (const int*)d_in[1];
    const float* W1 = (const float*)d_in[2];
    const float* b1 = (const float*)d_in[3];
    const float* W2 = (const float*)d_in[4];
    const float* b2 = (const float*)d_in[5];
    float* out = (float*)d_out;

    int n = in_sizes[0] / F_IN;        // 100000
    int E = in_sizes[1] / 2;           // 3200000
    const int* src = ei;
    const int* dst = ei + E;
    int NB = (n + 127) >> 7;           // 782 dst buckets

    // workspace layout
    char* ws = (char*)d_ws;
    const size_t MB = 1024 * 1024;
    int*      bCnt  = (int*)  (ws);                      // NB ints
    int*      bBase = (int*)  (ws + 64 * 1024);          // NB+1 ints
    int*      bCur  = (int*)  (ws + 128 * 1024);         // NB ints
    int*      ptr   = (int*)  (ws + 192 * 1024);         // n+1 ints
    float*    dinv  = (float*)(ws + 1 * MB);             // n floats
    int*      sIdx  = (int*)     (ws + 2 * MB);          // E ints  (13 MB)
    int*      pkBuf = (int*)     (ws + 15 * MB);         // E ints  (13 MB)
    _Float16* bufA  = (_Float16*)(ws + 28 * MB);         // n*64 f16: h1, later g
    _Float16* bufB  = (_Float16*)(ws + 41 * MB);         // n*64 f16: h

    hipMemsetAsync(bCnt, 0, (size_t)NB * sizeof(int), stream);
    bucket_histo<<<(E + HCHUNK - 1) / HCHUNK, 256, 0, stream>>>(dst, E, bCnt, NB);
    scan_buckets<<<1, 256, 0, stream>>>(bCnt, bBase, bCur, NB, E);
    partition<<<(E + PART_CHUNK - 1) / PART_CHUNK, 256, 0, stream>>>(src, dst, bCur, pkBuf, E, NB);
    bucket_finalize<<<NB, 256, 0, stream>>>(bBase, pkBuf, ptr, dinv, sIdx, n, E);

    gemm1_mfma<<<(n + 63) / 64, 256, 0, stream>>>(x, W1, bufA, n);
    gather16<true ><<<(n + 3) / 4, 256, 0, stream>>>(ptr, sIdx, dinv, bufA, b1, bufB, n); // h
    gather16<false><<<(n + 3) / 4, 256, 0, stream>>>(ptr, sIdx, dinv, bufB, b1, bufA, n); // g
    gemm2_mfma_logsm<<<(n + 63) / 64, 256, 0, stream>>>(bufA, W2, b2, out, n);
}

// Round 10
// 355.796 us; speedup vs baseline: 1.1962x; 1.0216x over previous
//
#include <hip/hip_runtime.h>
#include <math.h>

#define F_IN 128
#define HID  64
#define NCLS 40
#define HCHUNK 4096
#define PART_CHUNK 4096
#define MAXNB 1024

typedef _Float16 half8 __attribute__((ext_vector_type(8)));
typedef _Float16 half2t __attribute__((ext_vector_type(2)));
typedef float floatx4 __attribute__((ext_vector_type(4)));

// load 8 f16 from an 8B-aligned (not necessarily 16B) pointer (LDS staging use)
__device__ inline half8 ld_half8_u8(const _Float16* p) {
    union { uint2 u[2]; half8 h; } r;
    r.u[0] = *(const uint2*)p;
    r.u[1] = *(const uint2*)(p + 4);
    return r.h;
}

// ---------------- bucket-level histogram (LDS-privatized, 782 bins) ----------------
__global__ __launch_bounds__(256) void bucket_histo(const int* __restrict__ dst, int E,
                                                    int* __restrict__ bCnt, int NB) {
    __shared__ int h[MAXNB];
    int tid = threadIdx.x;
    for (int i = tid; i < NB; i += 256) h[i] = 0;
    __syncthreads();
    int e0 = blockIdx.x * HCHUNK;
    int eend = e0 + HCHUNK; if (eend > E) eend = E;
    for (int e = e0 + tid; e < eend; e += 256)
        atomicAdd(&h[dst[e] >> 7], 1);
    __syncthreads();
    for (int b = tid; b < NB; b += 256) {
        int c = h[b];
        if (c) atomicAdd(&bCnt[b], c);
    }
}

// ---------------- single-block exclusive scan of bucket counts ----------------
__global__ __launch_bounds__(256) void scan_buckets(const int* __restrict__ bCnt,
                                                    int* __restrict__ bBase,
                                                    int* __restrict__ bCur, int NB, int E) {
    __shared__ int part[256];
    int tid = threadIdx.x;
    int v[4]; int sum = 0;
#pragma unroll
    for (int k = 0; k < 4; ++k) {
        int i = tid * 4 + k;
        v[k] = (i < NB) ? bCnt[i] : 0;
        sum += v[k];
    }
    part[tid] = sum; __syncthreads();
    for (int off = 1; off < 256; off <<= 1) {
        int t = (tid >= off) ? part[tid - off] : 0;
        __syncthreads();
        part[tid] += t;
        __syncthreads();
    }
    int base = part[tid] - sum;   // exclusive
#pragma unroll
    for (int k = 0; k < 4; ++k) {
        int i = tid * 4 + k;
        if (i < NB) { bBase[i] = base; bCur[i] = base; }
        base += v[k];
    }
    if (tid == 255) bBase[NB] = E;
}

// ---------------- partition edges into 128-node dst buckets (packed: src<<7 | dst&127) ------
__global__ __launch_bounds__(256) void partition(const int* __restrict__ src,
                                                 const int* __restrict__ dst,
                                                 int* __restrict__ bCur,
                                                 int* __restrict__ pkBuf, int E, int NB) {
    __shared__ int hcnt[MAXNB];
    __shared__ int hbase[MAXNB];
    int tid = threadIdx.x;
    for (int i = tid; i < NB; i += 256) hcnt[i] = 0;
    __syncthreads();
    int e0 = blockIdx.x * PART_CHUNK;
    int s_[16], d_[16];
#pragma unroll
    for (int i = 0; i < 16; ++i) {
        int e = e0 + i * 256 + tid;
        if (e < E) {
            s_[i] = src[e]; d_[i] = dst[e];
            atomicAdd(&hcnt[d_[i] >> 7], 1);
        }
    }
    __syncthreads();
    for (int b = tid; b < NB; b += 256) {
        int c = hcnt[b];
        hbase[b] = c ? atomicAdd(&bCur[b], c) : 0;
        hcnt[b] = 0;
    }
    __syncthreads();
#pragma unroll
    for (int i = 0; i < 16; ++i) {
        int e = e0 + i * 256 + tid;
        if (e < E) {
            int b = d_[i] >> 7;
            int loc = atomicAdd(&hcnt[b], 1);
            pkBuf[hbase[b] + loc] = (s_[i] << 7) | (d_[i] & 127);
        }
    }
}

// ---------------- per-bucket: node counts -> ptr + dinv, then exact scatter to CSR ----------
__global__ __launch_bounds__(256) void bucket_finalize(const int* __restrict__ bBase,
                                                       const int* __restrict__ pkBuf,
                                                       int* __restrict__ ptr,
                                                       float* __restrict__ dinv,
                                                       int* __restrict__ sIdx, int n, int E) {
    __shared__ int cnt128[128];
    __shared__ int sc[128];
    __shared__ int cur[128];
    int b = blockIdx.x;
    int node0 = b << 7;
    int tid = threadIdx.x;
    if (tid < 128) cnt128[tid] = 0;
    __syncthreads();
    int beg = bBase[b], end = bBase[b + 1];
    for (int j = beg + tid; j < end; j += 256)
        atomicAdd(&cnt128[pkBuf[j] & 127], 1);
    __syncthreads();
    int v = (tid < 128) ? cnt128[tid] : 0;
    if (tid < 128) sc[tid] = v;
    __syncthreads();
    for (int off = 1; off < 128; off <<= 1) {
        int t = (tid < 128 && tid >= off) ? sc[tid - off] : 0;
        __syncthreads();
        if (tid < 128) sc[tid] += t;
        __syncthreads();
    }
    if (tid < 128) {
        int node = node0 + tid;
        if (node < n) {
            int p = beg + sc[tid] - v;
            ptr[node] = p;
            cur[tid] = p;
            dinv[node] = rsqrtf((float)v + 1.0f);   // +1 self loop
        }
    }
    if (tid == 0 && b == gridDim.x - 1) ptr[n] = E;
    __syncthreads();
    for (int j = beg + tid; j < end; j += 256) {
        int p = pkBuf[j];
        int pos = atomicAdd(&cur[p & 127], 1);
        sIdx[pos] = p >> 7;
    }
}

// ---------------- layer 1 GEMM via f16 MFMA: h1 = f16(x @ W1) ----------------
#define ASTRIDE 132   // f16 row stride (128 + 4 pad)
__global__ __launch_bounds__(256) void gemm1_mfma(const float* __restrict__ x,
                                                  const float* __restrict__ W1,
                                                  _Float16* __restrict__ h1, int n) {
    __shared__ _Float16 Ah[64 * ASTRIDE];
    __shared__ _Float16 Wt[64 * ASTRIDE];
    int tid = threadIdx.x;
    int node0 = blockIdx.x * 64;
#pragma unroll
    for (int i = 0; i < 8; ++i) {          // 8*256*4 = 8192 floats = 64 rows x 128 cols
        int f = (i * 256 + tid) * 4;
        int m = f >> 7, k = f & 127;
        float4 v = (node0 + m < n) ? ((const float4*)(x + (size_t)(node0 + m) * F_IN))[k >> 2]
                                   : make_float4(0.f, 0.f, 0.f, 0.f);
        _Float16* p = &Ah[m * ASTRIDE + k];
        p[0] = (_Float16)v.x; p[1] = (_Float16)v.y; p[2] = (_Float16)v.z; p[3] = (_Float16)v.w;
    }
#pragma unroll
    for (int i = 0; i < 32; ++i) {
        int f = i * 256 + tid;              // f = k*64 + nout
        int k = f >> 6, nn = f & 63;
        Wt[nn * ASTRIDE + k] = (_Float16)W1[f];
    }
    __syncthreads();
    int wave = tid >> 6, lane = tid & 63;
    int m0 = wave * 16;
    int col = lane & 15, quad = lane >> 4;
    floatx4 acc[4] = {{0,0,0,0},{0,0,0,0},{0,0,0,0},{0,0,0,0}};
#pragma unroll
    for (int kk = 0; kk < 4; ++kk) {
        int kbase = kk * 32 + quad * 8;
        half8 a = ld_half8_u8(&Ah[(m0 + col) * ASTRIDE + kbase]);
#pragma unroll
        for (int t = 0; t < 4; ++t) {
            half8 b = ld_half8_u8(&Wt[(t * 16 + col) * ASTRIDE + kbase]);
            acc[t] = __builtin_amdgcn_mfma_f32_16x16x32_f16(a, b, acc[t], 0, 0, 0);
        }
    }
#pragma unroll
    for (int t = 0; t < 4; ++t)
#pragma unroll
        for (int r = 0; r < 4; ++r) {
            int node = node0 + m0 + quad * 4 + r;
            if (node < n) h1[(size_t)node * HID + t * 16 + col] = (_Float16)acc[t][r];
        }
}

// ---------------- CSR gather: 4 nodes/wave, 16 lanes/node (2 slots x 8 chunks), x2 unroll ----
// 8 edges per node per iteration -> 32 row loads in flight per wave; 1-round reduction.
template<bool RELU>
__global__ __launch_bounds__(256) void gather4(const int* __restrict__ ptr,
                                               const int* __restrict__ sIdx,
                                               const float* __restrict__ dinv,
                                               const _Float16* __restrict__ hin,
                                               const float* __restrict__ bias,
                                               _Float16* __restrict__ hout, int n) {
    int tid = threadIdx.x, wave = tid >> 6, lane = tid & 63;
    int ng   = lane >> 4;         // node group 0..3
    int slot = (lane >> 3) & 1;   // edge slot 0..1
    int fq   = lane & 7;          // 16B chunk within 128B row
    int node = blockIdx.x * 16 + wave * 4 + ng;
    bool valid = node < n;
    int nodeC = valid ? node : 0;
    int beg = ptr[nodeC];
    int end = valid ? ptr[nodeC + 1] : beg;
    float di = dinv[nodeC];
    float a0[8] = {0,0,0,0,0,0,0,0}, a1[8] = {0,0,0,0,0,0,0,0};

    if (slot == 0 && valid) {     // self loop
        half8 v = *(const half8*)(hin + nodeC * HID + fq * 8);
        float w = di * di;
#pragma unroll
        for (int j = 0; j < 8; ++j) a0[j] = (float)v[j] * w;
    }
    for (int j0 = beg; j0 < end; j0 += 8) {
        int ja = j0 + slot, jb = j0 + 2 + slot, jc = j0 + 4 + slot, jd = j0 + 6 + slot;
        bool va = ja < end, vb = jb < end, vc = jc < end, vd = jd < end;
        int sa = sIdx[va ? ja : beg];
        int sb = sIdx[vb ? jb : beg];
        int sc_ = sIdx[vc ? jc : beg];
        int sd = sIdx[vd ? jd : beg];
        float wa = va ? dinv[sa] * di : 0.f;
        float wb = vb ? dinv[sb] * di : 0.f;
        float wc = vc ? dinv[sc_] * di : 0.f;
        float wd = vd ? dinv[sd] * di : 0.f;
        half8 ra = *(const half8*)(hin + sa * HID + fq * 8);
        half8 rb = *(const half8*)(hin + sb * HID + fq * 8);
        half8 rc = *(const half8*)(hin + sc_ * HID + fq * 8);
        half8 rd = *(const half8*)(hin + sd * HID + fq * 8);
#if __has_builtin(__builtin_amdgcn_fdot2)
        half2t wab = { (_Float16)wa, (_Float16)wb };
        half2t wcd = { (_Float16)wc, (_Float16)wd };
#pragma unroll
        for (int j = 0; j < 8; ++j) {
            half2t pab = { ra[j], rb[j] };
            half2t pcd = { rc[j], rd[j] };
            a0[j] = __builtin_amdgcn_fdot2(pab, wab, a0[j], false);
            a1[j] = __builtin_amdgcn_fdot2(pcd, wcd, a1[j], false);
        }
#else
#pragma unroll
        for (int j = 0; j < 8; ++j) {
            a0[j] = fmaf((float)ra[j], wa, a0[j]);
            a0[j] = fmaf((float)rb[j], wb, a0[j]);
            a1[j] = fmaf((float)rc[j], wc, a1[j]);
            a1[j] = fmaf((float)rd[j], wd, a1[j]);
        }
#endif
    }
#pragma unroll
    for (int j = 0; j < 8; ++j) {
        a0[j] += a1[j];
        a0[j] += __shfl_xor(a0[j], 8, 64);     // combine the 2 slots (1 round)
    }
    if (slot == 0 && valid) {
        union { half8 h; uint4 u; } o;
#pragma unroll
        for (int j = 0; j < 8; ++j) {
            float v = a0[j];
            if (RELU) v = fmaxf(v + bias[fq * 8 + j], 0.f);
            o.h[j] = (_Float16)v;
        }
        *(uint4*)(hout + nodeC * HID + fq * 8) = o.u;
    }
}

// ---------------- out = log_softmax(g @ W2 + b2) via MFMA, 64 nodes/block ----------------
#define GSTRIDE 72    // f16 row stride (64 + 8 pad)
__global__ __launch_bounds__(256) void gemm2_mfma_logsm(const _Float16* __restrict__ g,
                                                        const float* __restrict__ W2,
                                                        const float* __restrict__ b2,
                                                        float* __restrict__ out, int n) {
    __shared__ _Float16 gt[64 * GSTRIDE];   // 9216 B
    __shared__ _Float16 wt[48 * GSTRIDE];   // 6912 B, W2^T zero-padded to 48 cols
    int tid = threadIdx.x;
    int node0 = blockIdx.x * 64;
#pragma unroll
    for (int i = 0; i < 2; ++i) {           // 2*256*8 = 4096 f16 = 64 rows x 64 cols EXACTLY
        int f = (i * 256 + tid) * 8;
        int m = f >> 6, k = f & 63;
        union { uint4 u; half8 h; } v;
        if (node0 + m < n) v.u = *(const uint4*)(g + (size_t)(node0 + m) * HID + k);
        else v.u = make_uint4(0, 0, 0, 0);
        *(uint4*)&gt[m * GSTRIDE + k] = v.u;
    }
#pragma unroll
    for (int i = 0; i < 12; ++i) {          // stage W2^T (f32 -> f16), 3072 elems
        int f = i * 256 + tid;              // f = c*64 + k
        int c = f >> 6, k = f & 63;
        wt[c * GSTRIDE + k] = (c < NCLS) ? (_Float16)W2[k * NCLS + c] : (_Float16)0.f;
    }
    __syncthreads();

    int wave = tid >> 6, lane = tid & 63;
    int m0 = wave * 16;
    int col = lane & 15, quad = lane >> 4;
    floatx4 acc[3] = {{0,0,0,0},{0,0,0,0},{0,0,0,0}};
#pragma unroll
    for (int kk = 0; kk < 2; ++kk) {
        int kbase = kk * 32 + quad * 8;
        half8 a = *(const half8*)&gt[(m0 + col) * GSTRIDE + kbase];   // A[m=col][k]
#pragma unroll
        for (int t = 0; t < 3; ++t) {
            half8 b = *(const half8*)&wt[(t * 16 + col) * GSTRIDE + kbase]; // B[k][c=col]
            acc[t] = __builtin_amdgcn_mfma_f32_16x16x32_f16(a, b, acc[t], 0, 0, 0);
        }
    }
    // epilogue: per row (node) max/sum across the 16 lanes of this quad, 3 col-tiles
    float bb[3];
#pragma unroll
    for (int t = 0; t < 3; ++t) {
        int c = t * 16 + col;
        bb[t] = (c < NCLS) ? b2[c] : 0.f;
    }
#pragma unroll
    for (int r = 0; r < 4; ++r) {
        int node = node0 + m0 + quad * 4 + r;
        float v0 = acc[0][r] + bb[0];
        float v1 = acc[1][r] + bb[1];
        float v2 = (col < 8) ? acc[2][r] + bb[2] : -INFINITY;
        float m = fmaxf(fmaxf(v0, v1), v2);
#pragma unroll
        for (int off = 1; off < 16; off <<= 1) m = fmaxf(m, __shfl_xor(m, off, 64));
        float s = expf(v0 - m) + expf(v1 - m) + ((col < 8) ? expf(v2 - m) : 0.f);
#pragma unroll
        for (int off = 1; off < 16; off <<= 1) s += __shfl_xor(s, off, 64);
        float ls = logf(s);
        if (node < n) {
            float* op = out + (size_t)node * NCLS;
            op[col]      = v0 - m - ls;
            op[16 + col] = v1 - m - ls;
            if (col < 8) op[32 + col] = v2 - m - ls;
        }
    }
}

extern "C" void kernel_launch(void* const* d_in, const int* in_sizes, int n_in,
                              void* d_out, int out_size, void* d_ws, size_t ws_size,
                              hipStream_t stream) {
    const float* x  = (const float*)d_in[0];
    const int*   ei = (const int*)d_in[1];
    const float* W1 = (const float*)d_in[2];
    const float* b1 = (const float*)d_in[3];
    const float* W2 = (const float*)d_in[4];
    const float* b2 = (const float*)d_in[5];
    float* out = (float*)d_out;

    int n = in_sizes[0] / F_IN;        // 100000
    int E = in_sizes[1] / 2;           // 3200000
    const int* src = ei;
    const int* dst = ei + E;
    int NB = (n + 127) >> 7;           // 782 dst buckets

    // workspace layout
    char* ws = (char*)d_ws;
    const size_t MB = 1024 * 1024;
    int*      bCnt  = (int*)  (ws);                      // NB ints
    int*      bBase = (int*)  (ws + 64 * 1024);          // NB+1 ints
    int*      bCur  = (int*)  (ws + 128 * 1024);         // NB ints
    int*      ptr   = (int*)  (ws + 192 * 1024);         // n+1 ints
    float*    dinv  = (float*)(ws + 1 * MB);             // n floats
    int*      sIdx  = (int*)     (ws + 2 * MB);          // E ints  (13 MB)
    int*      pkBuf = (int*)     (ws + 15 * MB);         // E ints  (13 MB)
    _Float16* bufA  = (_Float16*)(ws + 28 * MB);         // n*64 f16: h1, later g
    _Float16* bufB  = (_Float16*)(ws + 41 * MB);         // n*64 f16: h

    hipMemsetAsync(bCnt, 0, (size_t)NB * sizeof(int), stream);
    bucket_histo<<<(E + HCHUNK - 1) / HCHUNK, 256, 0, stream>>>(dst, E, bCnt, NB);
    scan_buckets<<<1, 256, 0, stream>>>(bCnt, bBase, bCur, NB, E);
    partition<<<(E + PART_CHUNK - 1) / PART_CHUNK, 256, 0, stream>>>(src, dst, bCur, pkBuf, E, NB);
    bucket_finalize<<<NB, 256, 0, stream>>>(bBase, pkBuf, ptr, dinv, sIdx, n, E);

    gemm1_mfma<<<(n + 63) / 64, 256, 0, stream>>>(x, W1, bufA, n);
    gather4<true ><<<(n + 15) / 16, 256, 0, stream>>>(ptr, sIdx, dinv, bufA, b1, bufB, n); // h
    gather4<false><<<(n + 15) / 16, 256, 0, stream>>>(ptr, sIdx, dinv, bufB, b1, bufA, n); // g
    gemm2_mfma_logsm<<<(n + 63) / 64, 256, 0, stream>>>(bufA, W2, b2, out, n);
}

// Round 11
// 328.301 us; speedup vs baseline: 1.2964x; 1.0838x over previous
//
#include <hip/hip_runtime.h>
#include <math.h>

#define F_IN 128
#define HID  64
#define NCLS 40
#define PART_CHUNK 4096
#define CAP 4608          // fixed bucket capacity: mean 4096, sigma 64 -> 8.5 sigma headroom
#define MAXNB 1024
#define ASTRIDE 132       // f16 row stride (128 + 4 pad)

typedef _Float16 half8 __attribute__((ext_vector_type(8)));
typedef _Float16 half2t __attribute__((ext_vector_type(2)));
typedef float floatx4 __attribute__((ext_vector_type(4)));

// load 8 f16 from an 8B-aligned (not necessarily 16B) pointer (LDS staging use)
__device__ inline half8 ld_half8_u8(const _Float16* p) {
    union { uint2 u[2]; half8 h; } r;
    r.u[0] = *(const uint2*)p;
    r.u[1] = *(const uint2*)(p + 4);
    return r.h;
}

// ---------------- fused: [0,nPart) edge partition | [nPart, nPart+nGemm) gemm1 ----------------
// partition: 128-node dst buckets, fixed-capacity CAP regions of pkBuf, packed (src<<7|dst&127).
// gemm1: h1 = f16(x @ W1) via 16x16x32 f16 MFMA, 64 nodes/block.
__global__ __launch_bounds__(256) void fused_part_gemm1(const int* __restrict__ src,
                                                        const int* __restrict__ dst,
                                                        int* __restrict__ bCur,
                                                        int* __restrict__ pkBuf,
                                                        int E, int NB, int nPart,
                                                        const float* __restrict__ x,
                                                        const float* __restrict__ W1,
                                                        _Float16* __restrict__ h1, int n) {
    __shared__ __align__(16) char smem[2 * 64 * ASTRIDE * 2];   // 33792 B arena
    int tid = threadIdx.x;
    if ((int)blockIdx.x < nPart) {
        // ---- partition path ----
        int* hcnt  = (int*)smem;           // [MAXNB]
        int* hbase = (int*)smem + MAXNB;   // [MAXNB]
        for (int i = tid; i < NB; i += 256) hcnt[i] = 0;
        __syncthreads();
        int e0 = blockIdx.x * PART_CHUNK;
        int s_[16], d_[16];
#pragma unroll
        for (int i = 0; i < 16; ++i) {
            int e = e0 + i * 256 + tid;
            if (e < E) {
                s_[i] = src[e]; d_[i] = dst[e];
                atomicAdd(&hcnt[d_[i] >> 7], 1);
            }
        }
        __syncthreads();
        for (int b = tid; b < NB; b += 256) {
            int c = hcnt[b];
            hbase[b] = c ? (b * CAP + atomicAdd(&bCur[b], c)) : 0;
            hcnt[b] = 0;
        }
        __syncthreads();
#pragma unroll
        for (int i = 0; i < 16; ++i) {
            int e = e0 + i * 256 + tid;
            if (e < E) {
                int b = d_[i] >> 7;
                int loc = atomicAdd(&hcnt[b], 1);
                pkBuf[hbase[b] + loc] = (s_[i] << 7) | (d_[i] & 127);
            }
        }
    } else {
        // ---- gemm1 path ----
        _Float16* Ah = (_Float16*)smem;            // 64*ASTRIDE
        _Float16* Wt = Ah + 64 * ASTRIDE;          // 64*ASTRIDE
        int node0 = ((int)blockIdx.x - nPart) * 64;
#pragma unroll
        for (int i = 0; i < 8; ++i) {              // 8*256*4 = 8192 floats = 64x128
            int f = (i * 256 + tid) * 4;
            int m = f >> 7, k = f & 127;
            float4 v = (node0 + m < n) ? ((const float4*)(x + (size_t)(node0 + m) * F_IN))[k >> 2]
                                       : make_float4(0.f, 0.f, 0.f, 0.f);
            _Float16* p = &Ah[m * ASTRIDE + k];
            p[0] = (_Float16)v.x; p[1] = (_Float16)v.y; p[2] = (_Float16)v.z; p[3] = (_Float16)v.w;
        }
#pragma unroll
        for (int i = 0; i < 32; ++i) {
            int f = i * 256 + tid;                 // f = k*64 + nout
            int k = f >> 6, nn = f & 63;
            Wt[nn * ASTRIDE + k] = (_Float16)W1[f];
        }
        __syncthreads();
        int wave = tid >> 6, lane = tid & 63;
        int m0 = wave * 16;
        int col = lane & 15, quad = lane >> 4;
        floatx4 acc[4] = {{0,0,0,0},{0,0,0,0},{0,0,0,0},{0,0,0,0}};
#pragma unroll
        for (int kk = 0; kk < 4; ++kk) {
            int kbase = kk * 32 + quad * 8;
            half8 a = ld_half8_u8(&Ah[(m0 + col) * ASTRIDE + kbase]);
#pragma unroll
            for (int t = 0; t < 4; ++t) {
                half8 b = ld_half8_u8(&Wt[(t * 16 + col) * ASTRIDE + kbase]);
                acc[t] = __builtin_amdgcn_mfma_f32_16x16x32_f16(a, b, acc[t], 0, 0, 0);
            }
        }
#pragma unroll
        for (int t = 0; t < 4; ++t)
#pragma unroll
            for (int r = 0; r < 4; ++r) {
                int node = node0 + m0 + quad * 4 + r;
                if (node < n) h1[(size_t)node * HID + t * 16 + col] = (_Float16)acc[t][r];
            }
    }
}

// ---------------- exclusive scan of bucket fill counts -> global sIdx bases ----------------
__global__ __launch_bounds__(256) void scan_buckets(const int* __restrict__ bCur,
                                                    int* __restrict__ bBase, int NB, int E) {
    __shared__ int part[256];
    int tid = threadIdx.x;
    int v[4]; int sum = 0;
#pragma unroll
    for (int k = 0; k < 4; ++k) {
        int i = tid * 4 + k;
        v[k] = (i < NB) ? bCur[i] : 0;
        sum += v[k];
    }
    part[tid] = sum; __syncthreads();
    for (int off = 1; off < 256; off <<= 1) {
        int t = (tid >= off) ? part[tid - off] : 0;
        __syncthreads();
        part[tid] += t;
        __syncthreads();
    }
    int base = part[tid] - sum;   // exclusive
#pragma unroll
    for (int k = 0; k < 4; ++k) {
        int i = tid * 4 + k;
        if (i < NB) bBase[i] = base;
        base += v[k];
    }
    if (tid == 255) bBase[NB] = E;
}

// ---------------- per-bucket: node counts -> ptr + dinv, then exact scatter to CSR ----------
__global__ __launch_bounds__(256) void bucket_finalize(const int* __restrict__ bCur,
                                                       const int* __restrict__ bBase,
                                                       const int* __restrict__ pkBuf,
                                                       int* __restrict__ ptr,
                                                       float* __restrict__ dinv,
                                                       int* __restrict__ sIdx, int n, int E) {
    __shared__ int cnt128[128];
    __shared__ int sc[128];
    __shared__ int cur[128];
    int b = blockIdx.x;
    int node0 = b << 7;
    int tid = threadIdx.x;
    if (tid < 128) cnt128[tid] = 0;
    __syncthreads();
    int beg = b * CAP, end = beg + bCur[b];
    int dbase = bBase[b];
    for (int j = beg + tid; j < end; j += 256)
        atomicAdd(&cnt128[pkBuf[j] & 127], 1);
    __syncthreads();
    int v = (tid < 128) ? cnt128[tid] : 0;
    if (tid < 128) sc[tid] = v;
    __syncthreads();
    for (int off = 1; off < 128; off <<= 1) {
        int t = (tid < 128 && tid >= off) ? sc[tid - off] : 0;
        __syncthreads();
        if (tid < 128) sc[tid] += t;
        __syncthreads();
    }
    if (tid < 128) {
        int node = node0 + tid;
        if (node < n) {
            int p = dbase + sc[tid] - v;       // global CSR offset
            ptr[node] = p;
            cur[tid] = p;
            dinv[node] = rsqrtf((float)v + 1.0f);   // +1 self loop
        }
    }
    if (tid == 0 && b == gridDim.x - 1) ptr[n] = E;
    __syncthreads();
    for (int j = beg + tid; j < end; j += 256) {
        int p = pkBuf[j];
        int pos = atomicAdd(&cur[p & 127], 1);
        sIdx[pos] = p >> 7;
    }
}

// ---------------- CSR gather: 4 nodes/wave, 16 lanes/node (2 slots x 8 chunks), x2 unroll ----
template<bool RELU>
__global__ __launch_bounds__(256) void gather4(const int* __restrict__ ptr,
                                               const int* __restrict__ sIdx,
                                               const float* __restrict__ dinv,
                                               const _Float16* __restrict__ hin,
                                               const float* __restrict__ bias,
                                               _Float16* __restrict__ hout, int n) {
    int tid = threadIdx.x, wave = tid >> 6, lane = tid & 63;
    int ng   = lane >> 4;         // node group 0..3
    int slot = (lane >> 3) & 1;   // edge slot 0..1
    int fq   = lane & 7;          // 16B chunk within 128B row
    int node = blockIdx.x * 16 + wave * 4 + ng;
    bool valid = node < n;
    int nodeC = valid ? node : 0;
    int beg = ptr[nodeC];
    int end = valid ? ptr[nodeC + 1] : beg;
    float di = dinv[nodeC];
    float a0[8] = {0,0,0,0,0,0,0,0}, a1[8] = {0,0,0,0,0,0,0,0};

    if (slot == 0 && valid) {     // self loop
        half8 v = *(const half8*)(hin + nodeC * HID + fq * 8);
        float w = di * di;
#pragma unroll
        for (int j = 0; j < 8; ++j) a0[j] = (float)v[j] * w;
    }
    for (int j0 = beg; j0 < end; j0 += 8) {
        int ja = j0 + slot, jb = j0 + 2 + slot, jc = j0 + 4 + slot, jd = j0 + 6 + slot;
        bool va = ja < end, vb = jb < end, vc = jc < end, vd = jd < end;
        int sa = sIdx[va ? ja : beg];
        int sb = sIdx[vb ? jb : beg];
        int sc_ = sIdx[vc ? jc : beg];
        int sd = sIdx[vd ? jd : beg];
        float wa = va ? dinv[sa] * di : 0.f;
        float wb = vb ? dinv[sb] * di : 0.f;
        float wc = vc ? dinv[sc_] * di : 0.f;
        float wd = vd ? dinv[sd] * di : 0.f;
        half8 ra = *(const half8*)(hin + sa * HID + fq * 8);
        half8 rb = *(const half8*)(hin + sb * HID + fq * 8);
        half8 rc = *(const half8*)(hin + sc_ * HID + fq * 8);
        half8 rd = *(const half8*)(hin + sd * HID + fq * 8);
#if __has_builtin(__builtin_amdgcn_fdot2)
        half2t wab = { (_Float16)wa, (_Float16)wb };
        half2t wcd = { (_Float16)wc, (_Float16)wd };
#pragma unroll
        for (int j = 0; j < 8; ++j) {
            half2t pab = { ra[j], rb[j] };
            half2t pcd = { rc[j], rd[j] };
            a0[j] = __builtin_amdgcn_fdot2(pab, wab, a0[j], false);
            a1[j] = __builtin_amdgcn_fdot2(pcd, wcd, a1[j], false);
        }
#else
#pragma unroll
        for (int j = 0; j < 8; ++j) {
            a0[j] = fmaf((float)ra[j], wa, a0[j]);
            a0[j] = fmaf((float)rb[j], wb, a0[j]);
            a1[j] = fmaf((float)rc[j], wc, a1[j]);
            a1[j] = fmaf((float)rd[j], wd, a1[j]);
        }
#endif
    }
#pragma unroll
    for (int j = 0; j < 8; ++j) {
        a0[j] += a1[j];
        a0[j] += __shfl_xor(a0[j], 8, 64);     // combine the 2 slots (1 round)
    }
    if (slot == 0 && valid) {
        union { half8 h; uint4 u; } o;
#pragma unroll
        for (int j = 0; j < 8; ++j) {
            float v = a0[j];
            if (RELU) v = fmaxf(v + bias[fq * 8 + j], 0.f);
            o.h[j] = (_Float16)v;
        }
        *(uint4*)(hout + nodeC * HID + fq * 8) = o.u;
    }
}

// ---------------- out = log_softmax(g @ W2 + b2) via MFMA, 64 nodes/block ----------------
#define GSTRIDE 72    // f16 row stride (64 + 8 pad)
__global__ __launch_bounds__(256) void gemm2_mfma_logsm(const _Float16* __restrict__ g,
                                                        const float* __restrict__ W2,
                                                        const float* __restrict__ b2,
                                                        float* __restrict__ out, int n) {
    __shared__ _Float16 gt[64 * GSTRIDE];   // 9216 B
    __shared__ _Float16 wt[48 * GSTRIDE];   // 6912 B, W2^T zero-padded to 48 cols
    int tid = threadIdx.x;
    int node0 = blockIdx.x * 64;
#pragma unroll
    for (int i = 0; i < 2; ++i) {           // 2*256*8 = 4096 f16 = 64x64 EXACTLY
        int f = (i * 256 + tid) * 8;
        int m = f >> 6, k = f & 63;
        union { uint4 u; half8 h; } v;
        if (node0 + m < n) v.u = *(const uint4*)(g + (size_t)(node0 + m) * HID + k);
        else v.u = make_uint4(0, 0, 0, 0);
        *(uint4*)&gt[m * GSTRIDE + k] = v.u;
    }
#pragma unroll
    for (int i = 0; i < 12; ++i) {          // stage W2^T (f32 -> f16), 3072 elems
        int f = i * 256 + tid;              // f = c*64 + k
        int c = f >> 6, k = f & 63;
        wt[c * GSTRIDE + k] = (c < NCLS) ? (_Float16)W2[k * NCLS + c] : (_Float16)0.f;
    }
    __syncthreads();

    int wave = tid >> 6, lane = tid & 63;
    int m0 = wave * 16;
    int col = lane & 15, quad = lane >> 4;
    floatx4 acc[3] = {{0,0,0,0},{0,0,0,0},{0,0,0,0}};
#pragma unroll
    for (int kk = 0; kk < 2; ++kk) {
        int kbase = kk * 32 + quad * 8;
        half8 a = *(const half8*)&gt[(m0 + col) * GSTRIDE + kbase];   // A[m=col][k]
#pragma unroll
        for (int t = 0; t < 3; ++t) {
            half8 b = *(const half8*)&wt[(t * 16 + col) * GSTRIDE + kbase]; // B[k][c=col]
            acc[t] = __builtin_amdgcn_mfma_f32_16x16x32_f16(a, b, acc[t], 0, 0, 0);
        }
    }
    float bb[3];
#pragma unroll
    for (int t = 0; t < 3; ++t) {
        int c = t * 16 + col;
        bb[t] = (c < NCLS) ? b2[c] : 0.f;
    }
#pragma unroll
    for (int r = 0; r < 4; ++r) {
        int node = node0 + m0 + quad * 4 + r;
        float v0 = acc[0][r] + bb[0];
        float v1 = acc[1][r] + bb[1];
        float v2 = (col < 8) ? acc[2][r] + bb[2] : -INFINITY;
        float m = fmaxf(fmaxf(v0, v1), v2);
#pragma unroll
        for (int off = 1; off < 16; off <<= 1) m = fmaxf(m, __shfl_xor(m, off, 64));
        float s = expf(v0 - m) + expf(v1 - m) + ((col < 8) ? expf(v2 - m) : 0.f);
#pragma unroll
        for (int off = 1; off < 16; off <<= 1) s += __shfl_xor(s, off, 64);
        float ls = logf(s);
        if (node < n) {
            float* op = out + (size_t)node * NCLS;
            op[col]      = v0 - m - ls;
            op[16 + col] = v1 - m - ls;
            if (col < 8) op[32 + col] = v2 - m - ls;
        }
    }
}

extern "C" void kernel_launch(void* const* d_in, const int* in_sizes, int n_in,
                              void* d_out, int out_size, void* d_ws, size_t ws_size,
                              hipStream_t stream) {
    const float* x  = (const float*)d_in[0];
    const int*   ei = (const int*)d_in[1];
    const float* W1 = (const float*)d_in[2];
    const float* b1 = (const float*)d_in[3];
    const float* W2 = (const float*)d_in[4];
    const float* b2 = (const float*)d_in[5];
    float* out = (float*)d_out;

    int n = in_sizes[0] / F_IN;        // 100000
    int E = in_sizes[1] / 2;           // 3200000
    const int* src = ei;
    const int* dst = ei + E;
    int NB = (n + 127) >> 7;           // 782 dst buckets
    int nPart = (E + PART_CHUNK - 1) / PART_CHUNK;   // 782
    int nGemm1 = (n + 63) / 64;                      // 1563

    // workspace layout
    char* ws = (char*)d_ws;
    const size_t MB = 1024 * 1024;
    int*      bCur  = (int*)  (ws);                      // NB ints
    int*      bBase = (int*)  (ws + 64 * 1024);          // NB+1 ints
    int*      ptr   = (int*)  (ws + 128 * 1024);         // n+1 ints (400 KB)
    float*    dinv  = (float*)(ws + 1 * MB);             // n floats
    int*      sIdx  = (int*)     (ws + 2 * MB);          // E ints  (12.8 MB)
    int*      pkBuf = (int*)     (ws + 15 * MB);         // NB*CAP ints (14.4 MB)
    _Float16* bufA  = (_Float16*)(ws + 30 * MB);         // n*64 f16: h1, later g
    _Float16* bufB  = (_Float16*)(ws + 43 * MB);         // n*64 f16: h

    hipMemsetAsync(bCur, 0, (size_t)NB * sizeof(int), stream);
    fused_part_gemm1<<<nPart + nGemm1, 256, 0, stream>>>(src, dst, bCur, pkBuf, E, NB, nPart,
                                                         x, W1, bufA, n);
    scan_buckets<<<1, 256, 0, stream>>>(bCur, bBase, NB, E);
    bucket_finalize<<<NB, 256, 0, stream>>>(bCur, bBase, pkBuf, ptr, dinv, sIdx, n, E);

    gather4<true ><<<(n + 15) / 16, 256, 0, stream>>>(ptr, sIdx, dinv, bufA, b1, bufB, n); // h
    gather4<false><<<(n + 15) / 16, 256, 0, stream>>>(ptr, sIdx, dinv, bufB, b1, bufA, n); // g
    gemm2_mfma_logsm<<<(n + 63) / 64, 256, 0, stream>>>(bufA, W2, b2, out, n);
}